// Round 2
// baseline (135.649 us; speedup 1.0000x reference)
//
#include <hip/hip_runtime.h>
#include <hip/hip_bf16.h>
#include <stdint.h>

typedef __attribute__((ext_vector_type(8))) short bf16x8;
typedef __attribute__((ext_vector_type(4))) float f32x4;
typedef __attribute__((ext_vector_type(16))) float f32x16;

#define MFMA16(a,b,c) __builtin_amdgcn_mfma_f32_16x16x32_bf16((a),(b),(c),0,0,0)
#define MFMA32(a,b,c) __builtin_amdgcn_mfma_f32_32x32x16_bf16((a),(b),(c),0,0,0)
#define AS1 __attribute__((address_space(1)))
#define AS3 __attribute__((address_space(3)))

__device__ inline short f2bf(float f) {
    union { __hip_bfloat16 h; short s; } u;
    u.h = __float2bfloat16(f);
    return u.s;
}
__device__ inline uint32_t pack_bf16(float a, float b) {
    union { __hip_bfloat16 h; uint16_t u; } ua, ub;
    ua.h = __float2bfloat16(a); ub.h = __float2bfloat16(b);
    return (uint32_t)ua.u | ((uint32_t)ub.u << 16);
}

// cross-half register exchange
#if __has_builtin(__builtin_amdgcn_permlane32_swap)
#define SWAP32(x, y, a, b) { auto _r = __builtin_amdgcn_permlane32_swap((a),(b),false,false); \
                             (x) = _r[0]; (y) = _r[1]; }
#else
#define SWAP32(x, y, a, b) { uint32_t _ta = __shfl_xor((uint32_t)(a),32); \
                             uint32_t _tb = __shfl_xor((uint32_t)(b),32); \
                             (x) = hh_ ? _tb : (a); (y) = hh_ ? (b) : _ta; }
#endif

// S' = S * scale * log2(e): fold into Wq so attention exp is native exp2.
#define QSCALE 0.12751879523879295f   // (1/sqrt(128)) * log2(e)

// ---------------------------------------------------------------------------
// Kernel 1: eff-weight mix -> bf16 W [3][8][128][512]; x f32 -> bf16
// ---------------------------------------------------------------------------
#define NW (8*128*512)        // 524288 per projection
#define NX4 (8192*512/4)      // 1048576 float4 chunks of x

__global__ void prep_kernel(const float* __restrict__ x,
                            const float* __restrict__ w,
                            const float* __restrict__ bK,
                            const float* __restrict__ bQ,
                            const float* __restrict__ bV,
                            short* __restrict__ xb,    // [8192][512]
                            short* __restrict__ W)     // [3][1024][512]  (K,Q,V)
{
    const float w0 = w[0], w1 = w[1], w2 = w[2], w3 = w[3];
    for (int i = blockIdx.x * blockDim.x + threadIdx.x; i < NW + NX4;
         i += gridDim.x * blockDim.x) {
        if (i < NW) {
            int e = i & 511;
            int d = (i >> 9) & 127;
            int h = i >> 16;
            float eff = 0.f;
            if (h < 4) { eff += w2; if (d < 64 && e < 256) eff += w0; }
            if (d < 32 && e < 256) eff += w1;
            if (d < 64) eff += w3;
            W[i]          = f2bf(eff * bK[i]);
            W[i + NW]     = f2bf(eff * bQ[i] * QSCALE);
            W[i + 2*NW]   = f2bf(eff * bV[i]);
        } else {
            int j = i - NW;
            float4 v = ((const float4*)x)[j];
            short4 o;
            o.x = f2bf(v.x); o.y = f2bf(v.y); o.z = f2bf(v.z); o.w = f2bf(v.w);
            ((short4*)xb)[j] = o;
        }
    }
}

// ---------------------------------------------------------------------------
// Kernel 2: C[8192,3072] = xb[8192,512] @ W[3072,512]^T
// K,Q stored [bh][t][d]; V stored TRANSPOSED as [bh][d][t].
// LDS-repacked coalesced epilogue; bijective XCD grid swizzle.
// ---------------------------------------------------------------------------
__global__ __launch_bounds__(256)
void proj_gemm(const short* __restrict__ A,    // [8192][512]
               const short* __restrict__ Bw,   // [3072][512]
               short* __restrict__ qkv)
{
    __shared__ short S[128 * 128];             // 32 KB: staging + repack
    short* As = S;                             // 16 KB
    short* Bs = S + 128 * 64;                  // 16 KB
    const int tid = threadIdx.x;
    const int lane = tid & 63;
    const int wave = tid >> 6;
    const int wr = wave >> 1, wc = wave & 1;
    const int l15 = lane & 15, lk = lane >> 4;

    // bijective XCD swizzle: 1536 blocks, 192 consecutive per XCD
    const int wg = (blockIdx.x & 7) * 192 + (blockIdx.x >> 3);
    const int bm = (wg / 24) * 128;
    const int bn = (wg % 24) * 128;

    char* Ab = (char*)As;
    char* Bb = (char*)Bs;
    char* Sb = (char*)S;
    f32x4 acc[4][4] = {};

    for (int k0 = 0; k0 < 512; k0 += 64) {
        __syncthreads();
#pragma unroll
        for (int i = 0; i < 4; ++i) {
            int c = i * 256 + tid;              // 0..1023, 16B chunk
            int lin = c * 16;                   // linear byte in 16 KB tile
            int row = lin >> 7;                 // 0..127
            int cof = ((lin & 127) ^ ((row & 7) << 4)) >> 1;   // shorts
            __builtin_amdgcn_global_load_lds(
                (const AS1 void*)(A + (size_t)(bm + row) * 512 + k0 + cof),
                (AS3 void*)(As + c * 8), 16, 0, 0);
            __builtin_amdgcn_global_load_lds(
                (const AS1 void*)(Bw + (size_t)(bn + row) * 512 + k0 + cof),
                (AS3 void*)(Bs + c * 8), 16, 0, 0);
        }
        __syncthreads();                        // drains vmcnt(0) (m97 pattern)
#pragma unroll
        for (int kk = 0; kk < 2; ++kk) {
            bf16x8 af[4], bfv[4];
#pragma unroll
            for (int mi = 0; mi < 4; ++mi) {
                int row = wr * 64 + mi * 16 + l15;
                af[mi] = *(const bf16x8*)(Ab + ((row * 128 + kk * 64 + lk * 16) ^ ((row & 7) << 4)));
            }
#pragma unroll
            for (int ni = 0; ni < 4; ++ni) {
                int row = wc * 64 + ni * 16 + l15;
                bfv[ni] = *(const bf16x8*)(Bb + ((row * 128 + kk * 64 + lk * 16) ^ ((row & 7) << 4)));
            }
#pragma unroll
            for (int mi = 0; mi < 4; ++mi)
#pragma unroll
                for (int ni = 0; ni < 4; ++ni)
                    acc[mi][ni] = MFMA16(af[mi], bfv[ni], acc[mi][ni]);
        }
    }

    // ---- epilogue: repack C-tile via LDS, store coalesced -----------------
    const int proj = bn >> 10;                  // uniform per block
    const int b = bm >> 11;
    const int bh = b * 8 + ((bn & 1023) >> 7);
    const int tbase = bm & 2047;

    __syncthreads();                            // staging reads done
    if (proj == 2) {
        // V: LDS T[dl][tl] (transpose), pack r-pairs (consecutive tl)
#pragma unroll
        for (int mi = 0; mi < 4; ++mi) {
#pragma unroll
            for (int ni = 0; ni < 4; ++ni) {
                int dl = wc * 64 + ni * 16 + l15;
                int tlb = wr * 64 + mi * 16 + lk * 4;
                int byte0 = (dl * 256 + tlb * 2) ^ ((dl & 7) << 4);
                *(uint32_t*)(Sb + byte0)     = pack_bf16(acc[mi][ni][0], acc[mi][ni][1]);
                *(uint32_t*)(Sb + byte0 + 4) = pack_bf16(acc[mi][ni][2], acc[mi][ni][3]);
            }
        }
    } else {
        // K/Q: LDS T[tl][dl]
#pragma unroll
        for (int mi = 0; mi < 4; ++mi) {
#pragma unroll
            for (int ni = 0; ni < 4; ++ni) {
                int dl = wc * 64 + ni * 16 + l15;
#pragma unroll
                for (int r = 0; r < 4; ++r) {
                    int tl = wr * 64 + mi * 16 + lk * 4 + r;
                    *(short*)(Sb + ((tl * 256 + dl * 2) ^ ((tl & 7) << 4))) = f2bf(acc[mi][ni][r]);
                }
            }
        }
    }
    __syncthreads();

    short* dst;
    if (proj == 2)
        dst = qkv + (size_t)2 * (32 * 2048 * 128) + (size_t)bh * 128 * 2048;
    else
        dst = qkv + (size_t)proj * (32 * 2048 * 128) + (size_t)bh * 2048 * 128;

#pragma unroll
    for (int i = 0; i < 8; ++i) {
        int c = i * 256 + tid;                  // 0..2047 16B chunks
        int row = c >> 4;
        uint4 v = *(const uint4*)(Sb + row * 256 + (((c & 15) * 16) ^ ((row & 7) << 4)));
        if (proj == 2) {
            // row = d, cols = t
            *(uint4*)(dst + (size_t)row * 2048 + tbase + (c & 15) * 8) = v;
        } else {
            // row = t, cols = d
            *(uint4*)(dst + (size_t)(tbase + row) * 128 + (c & 15) * 8) = v;
        }
    }
}

// ---------------------------------------------------------------------------
// Kernel 3: causal flash attention — distance-3 prefetch pipeline.
// R1 post-mortem: dur flat because prefetch distance stayed 1 while per-tile
// compute cover halved; vmcnt stall ~1300 cyc/tile dominated.
// New structure:
//   - 32-kv tiles, 16 KB each (K 8K frag-major + V 8K frag-major), FOUR LDS
//     buffers (64 KB) -> stage tile j+3 while computing tile j. Steady-state
//     s_waitcnt vmcnt(12) (3 tiles in flight, never drained); tail 8/4/0.
//   - Frag-major LDS: ds_read_b128 reads 512B contiguous per 32-lane half ->
//     zero bank conflicts, no swizzle; global_load_lds src stays 16B-contig.
//   - 1024 blocks (64 q rows): waves = 2 q-chunks x 2 kv-PARITIES; a wave
//     computes full 32q x 32kv (dense 8+8 MFMA) on tiles of its parity,
//     crosses barriers on the others. End-of-kernel LDS flash-combine merges
//     parities. Backfill (4 blocks/CU queue-depth 2) balances the causal tail.
//   - XCD clustering: 4 bh per XCD (~4 MB KV = L2); big strips launch first.
// Dynamic LDS (65536 B): 4 x {K 8K | V 8K}
// ---------------------------------------------------------------------------
__device__ inline void stage_tile32(const short* __restrict__ Kp,
                                    const short* __restrict__ Vp,
                                    int j0, char* smem, int buf)
{
    short* kls = (short*)(smem + (buf << 14));   // 16 KB per buffer
    short* vls = kls + 4096;                     // +8 KB (shorts)
    const int tid = threadIdx.x;
    // K tile, frag-major: chunk c (0..511): slot = c>>5 (= dblk*2+hh), t = c&31
    // stores K[j0+t][slot*8 .. +8] at kls + c*8   (16B contiguous src)
#pragma unroll
    for (int i = 0; i < 2; ++i) {
        int c = i * 256 + tid;
        int slot = c >> 5, t = c & 31;
        __builtin_amdgcn_global_load_lds(
            (const AS1 void*)(Kp + (size_t)(j0 + t) * 128 + slot * 8),
            (AS3 void*)(kls + c * 8), 16, 0, 0);
    }
    // V tile, frag-major: chunk c (0..511): slot = c>>7 (= kb*2+hh), d = c&127
    // stores V[d][j0 + slot*8 .. +8] at vls + c*8  (V global is [d][t])
#pragma unroll
    for (int i = 0; i < 2; ++i) {
        int c = i * 256 + tid;
        int slot = c >> 7, d = c & 127;
        __builtin_amdgcn_global_load_lds(
            (const AS1 void*)(Vp + (size_t)d * 2048 + j0 + slot * 8),
            (AS3 void*)(vls + c * 8), 16, 0, 0);
    }
}

__global__ __launch_bounds__(256, 2)
void attn_kernel(const short* __restrict__ qkv, float* __restrict__ out)
{
    extern __shared__ char smem[];
    const int tid = threadIdx.x, lane = tid & 63, wave = tid >> 6;
    const int l31 = lane & 31;
    const int hh_ = lane >> 5;

    // XCD-clustered, big-first: x = XCD (round-robin assumption), 4 bh per
    // XCD (KV working set ~4MB = L2), strips descend so long blocks start
    // first and short ones backfill.
    const int x = blockIdx.x & 7;
    const int g = blockIdx.x >> 3;              // 0..127 per XCD
    const int bh = x * 4 + (g & 3);
    const int sp = 31 - (g >> 2);               // 64-row q strip, 31..0
    const int q0 = sp * 64;

    const int qw = wave & 1;                    // q sub-block (32 rows)
    const int kvp = wave >> 1;                  // kv tile PARITY this wave owns

    const size_t HSTRIDE = (size_t)2048 * 128;
    const short* Kp = qkv + (size_t)bh * HSTRIDE;                    // [t][d]
    const short* Qp = qkv + (size_t)32 * HSTRIDE + (size_t)bh * HSTRIDE;
    const short* Vp = qkv + (size_t)64 * HSTRIDE + (size_t)bh * HSTRIDE; // [d][t]

    // Q B-operand frags: lane holds Q[q0+qw*32+l31][dblk*16 + hh_*8 + j]
    bf16x8 qf[8];
    {
        const short* qrow = Qp + (size_t)(q0 + qw * 32 + l31) * 128 + hh_ * 8;
#pragma unroll
        for (int dblk = 0; dblk < 8; ++dblk)
            qf[dblk] = *(const bf16x8*)(qrow + dblk * 16);
    }

    // per-lane softmax state for q = l31 (dup across halves), exp2 domain
    float mrow = -1e30f, lrow = 0.f;
    f32x16 acco[4] = {};                        // O[q(reg)][dt*32 + l31]

    const int nt = 2 * sp + 2;                  // 32-kv tiles
    const int qwave = q0 + qw * 32;
    const int qglob = qwave + l31;

    // prologue: stage tiles 0,1,2 into buffers 0,1,2
    stage_tile32(Kp, Vp, 0,  smem, 0);
    stage_tile32(Kp, Vp, 32, smem, 1);
    stage_tile32(Kp, Vp, 64, smem, 2);

    for (int jt = 0; jt < nt; ++jt) {
        const int j0 = jt << 5;
        __builtin_amdgcn_s_barrier();           // buf (jt+3)&3 free (= jt-1's)
        if (jt + 3 < nt) {
            stage_tile32(Kp, Vp, (jt + 3) << 5, smem, (jt + 3) & 3);
            asm volatile("s_waitcnt vmcnt(12)" ::: "memory");  // 3 tiles in flight
        } else if (jt == nt - 3) {
            asm volatile("s_waitcnt vmcnt(8)" ::: "memory");
        } else if (jt == nt - 2) {
            asm volatile("s_waitcnt vmcnt(4)" ::: "memory");
        } else {
            asm volatile("s_waitcnt vmcnt(0)" ::: "memory");
        }
        __builtin_amdgcn_sched_barrier(0);
        __builtin_amdgcn_s_barrier();           // tile jt visible to all waves
        __builtin_amdgcn_sched_barrier(0);

        // parity + causal gating (wave-uniform)
        if (((jt & 1) == kvp) && (j0 <= qwave)) {
            const short* kls = (const short*)(smem + ((jt & 3) << 14));
            const short* vls = kls + 4096;

            // S'^T = K Q'^T : lane pair (l, l^32) holds S'[kv 0..31][q=l31]
            f32x16 sacc = {};
            __builtin_amdgcn_s_setprio(1);
#pragma unroll
            for (int dblk = 0; dblk < 8; ++dblk) {
                bf16x8 kf = *(const bf16x8*)(kls + dblk * 512 + hh_ * 256 + l31 * 8);
                sacc = MFMA32(kf, qf[dblk], sacc);
            }
            __builtin_amdgcn_s_setprio(0);

            // causal mask: only the j0 == qwave tile straddles
            if (j0 == qwave) {
#pragma unroll
                for (int r = 0; r < 16; ++r) {
                    int kvglob = j0 + (r & 3) + 8 * (r >> 2) + 4 * hh_;
                    if (kvglob > qglob) sacc[r] = -1e30f;
                }
            }

            // row max: in-lane tree + 1 cross-half shuffle
            float pmax = -1e30f;
#pragma unroll
            for (int r = 0; r < 16; r += 4) {
                float a = fmaxf(sacc[r], sacc[r + 1]);
                float b2 = fmaxf(sacc[r + 2], sacc[r + 3]);
                pmax = fmaxf(pmax, fmaxf(a, b2));
            }
            pmax = fmaxf(pmax, __shfl_xor(pmax, 32));

            // defer-max: rescale only when max grew by > 8 nats (11.54 bits)
            if (!__all(pmax - mrow <= 11.5416f)) {
                float mn = fmaxf(mrow, pmax);
                float alpha = __builtin_amdgcn_exp2f(mrow - mn);
                mrow = mn;
                lrow *= alpha;
#pragma unroll
                for (int r = 0; r < 16; ++r) {
                    float ar = __shfl(alpha, (r & 3) + 8 * (r >> 2) + 4 * hh_);
#pragma unroll
                    for (int dt = 0; dt < 4; ++dt) acco[dt][r] *= ar;
                }
            }

            // P = exp2(S' - m'), row sum, pack to bf16 pairs
            float psum = 0.f;
            uint32_t pkA[4], pkB[4];
#pragma unroll
            for (int sg = 0; sg < 4; ++sg) {
                float p0 = __builtin_amdgcn_exp2f(sacc[4 * sg + 0] - mrow);
                float p1 = __builtin_amdgcn_exp2f(sacc[4 * sg + 1] - mrow);
                float p2 = __builtin_amdgcn_exp2f(sacc[4 * sg + 2] - mrow);
                float p3 = __builtin_amdgcn_exp2f(sacc[4 * sg + 3] - mrow);
                psum += (p0 + p1) + (p2 + p3);
                pkA[sg] = pack_bf16(p0, p1);
                pkB[sg] = pack_bf16(p2, p3);
            }
            psum += __shfl_xor(psum, 32);
            lrow += psum;

            // O += P V  (P A-frags assembled in-register via cross-half swaps)
            __builtin_amdgcn_s_setprio(1);
#pragma unroll
            for (int kb = 0; kb < 2; ++kb) {
                uint32_t r0, r1, r2, r3;
                SWAP32(r0, r2, pkA[2 * kb], pkA[2 * kb + 1]);
                SWAP32(r1, r3, pkB[2 * kb], pkB[2 * kb + 1]);
                union { uint32_t u[4]; bf16x8 v; } pa;
                pa.u[0] = r0; pa.u[1] = r1; pa.u[2] = r2; pa.u[3] = r3;
#pragma unroll
                for (int dt = 0; dt < 4; ++dt) {
                    bf16x8 vf = *(const bf16x8*)(vls + (kb * 2 + hh_) * 1024 + (dt * 32 + l31) * 8);
                    acco[dt] = MFMA32(pa.v, vf, acco[dt]);
                }
            }
            __builtin_amdgcn_s_setprio(0);
        }
    }

    // ---- intra-block flash combine: merge kv parities (waves w and w+2) ---
    __syncthreads();                            // all waves done reading LDS
    float* ex = (float*)smem;                   // 2 waves x 4096 f32 (32 KB)
    float* ml = (float*)(smem + 32768);         // 2 waves x 64 x {m,l}
    if (kvp == 1) {
        float* dst = ex + qw * 4096;
#pragma unroll
        for (int dt = 0; dt < 4; ++dt)
#pragma unroll
            for (int r = 0; r < 16; ++r)
                dst[(dt * 16 + r) * 64 + lane] = acco[dt][r];
        ml[qw * 128 + lane * 2 + 0] = mrow;
        ml[qw * 128 + lane * 2 + 1] = lrow;
    }
    __syncthreads();
    if (kvp == 0) {
        float m1 = ml[qw * 128 + lane * 2 + 0];
        float l1 = ml[qw * 128 + lane * 2 + 1];
        float M  = fmaxf(mrow, m1);
        float a  = __builtin_amdgcn_exp2f(mrow - M);
        float b2 = __builtin_amdgcn_exp2f(m1 - M);   // 0 if parity had no work
        float lf = lrow * a + l1 * b2;
        float sA = a / lf, sB = b2 / lf;
        const float* src = ex + qw * 4096;
        const int b = bh >> 3, hd = bh & 7;
#pragma unroll
        for (int r = 0; r < 16; ++r) {
            int ql = (r & 3) + 8 * (r >> 2) + 4 * hh_;
            float sa = __shfl(sA, ql);
            float sb = __shfl(sB, ql);
            int t = qwave + ql;
            float* o = out + (size_t)(b * 2048 + t) * 1024 + hd * 128 + l31;
#pragma unroll
            for (int dt = 0; dt < 4; ++dt)
                o[dt * 32] = acco[dt][r] * sa + src[(dt * 16 + r) * 64 + lane] * sb;
        }
    }
}

// ---------------------------------------------------------------------------
extern "C" void kernel_launch(void* const* d_in, const int* in_sizes, int n_in,
                              void* d_out, int out_size, void* d_ws, size_t ws_size,
                              hipStream_t stream) {
    const float* x  = (const float*)d_in[0];
    const float* w  = (const float*)d_in[1];
    const float* bK = (const float*)d_in[2];
    const float* bQ = (const float*)d_in[3];
    const float* bV = (const float*)d_in[4];

    // workspace layout (bytes): xb 8,388,608 | W 3,145,728 | qkv 50,331,648
    short* xb  = (short*)d_ws;
    short* W   = (short*)((char*)d_ws + 8388608);
    short* qkv = (short*)((char*)d_ws + 8388608 + 3145728);
    float* out = (float*)d_out;

    // allow 64 KB dynamic LDS (idempotent; not a stream op, capture-safe)
    hipFuncSetAttribute((const void*)attn_kernel,
                        hipFuncAttributeMaxDynamicSharedMemorySize, 65536);

    prep_kernel<<<2048, 256, 0, stream>>>(x, w, bK, bQ, bV, xb, W);
    proj_gemm<<<64 * 24, 256, 0, stream>>>(xb, W, qkv);
    attn_kernel<<<32 * 32, 256, 65536, stream>>>(qkv, out);
}